// Round 19
// baseline (3332.039 us; speedup 1.0000x reference)
//
#include <hip/hip_runtime.h>
#include <math.h>

// ESN: 512 sequential steps of h = tanh([h | x_t] @ [W_hh|W_ih]^T + b)
// T=512, B=64, I=128, H=1024, K' = 1152.
//
// R23 (from R18 @ 2.55 ms; R21/R22 showed the 2-chain window has NO slack:
// publish->consume ~2.5us == delta ~2us + RT ~0.7us): FOUR independent
// 2-row chains per WG.
//  * Period = 4 phases. Chain C+1's LDS-DMA prefetch is issued at the START
//    of phase C: aged exactly 2 phases since publish (>= delta when phases
//    >~1us), flight = 1 full phase (>= RT). Both margins exist -- impossible
//    with 2 chains.
//  * Per-phase: consume (vmcnt0 + ds_read + poison check; blocking retry
//    fallback) -> issue next chain's DMA -> FMA (NB=2) -> reduce -> sync ->
//    epilogue (2 rows, waves 0-1 lanes 0-7) with fire-and-forget sc0sc1
//    16B publish.
//  * Kept: sentinel sync (out pre-poisoned 0x7F7F7F7F, data IS the flag),
//    wave-private k-slice staging (each wave owns k in [128w,128w+128) of
//    its chains' rows), W (18 float4) + bias VGPR-resident, x prefetch.
//  * Diagnostics: FETCH ~600-650MB = prefetch lands (win); FETCH >=750MB =
//    delta exceeds 2-phase aging (floor established).

#define T_STEPS 512
#define BATCH   64
#define HDIM    1024
#define IDIM    128
#define KDIM    1152
#define NWG     256
#define POISON  0x7F7F7F7Fu

typedef float f32x4_t __attribute__((ext_vector_type(4)));
typedef __attribute__((address_space(3))) void lds_void;
typedef __attribute__((address_space(1))) const void gm_void;

// async global->LDS DMA, 16B/lane, coherence-point read (SC0|SC1)
__device__ __forceinline__ void issue_dma16(const float* g, float* l) {
    __builtin_amdgcn_global_load_lds((gm_void*)g, (lds_void*)l, 16, 0, 17);
}

// wait all outstanding vmem (covers DMAs); "memory" clobber orders the
// following ds_read checks after it.
__device__ __forceinline__ void wait_vmem0(void) {
    asm volatile("s_waitcnt vmcnt(0)" ::: "memory");
}

// 16B coherence-point load + blocking drain (retry path)
__device__ __forceinline__ void sc_load1x4(const float* p, float4& a) {
    asm volatile("global_load_dwordx4 %0, %1, off sc0 sc1\n\ts_waitcnt vmcnt(0)"
                 : "=&v"(a) : "v"(p) : "memory");
}

// 16B write-through store (no drain: visibility rides the write)
__device__ __forceinline__ void sc_store4_nodrain(float* p, float4 v) {
    f32x4_t t;
    t.x = v.x; t.y = v.y; t.z = v.z; t.w = v.w;
    asm volatile("global_store_dwordx4 %0, %1, off sc0 sc1"
                 :: "v"(p), "v"(t) : "memory");
}

__device__ __forceinline__ unsigned chk4(float4 v) {
    return (unsigned)((__float_as_uint(v.x) == POISON) |
                      (__float_as_uint(v.y) == POISON) |
                      (__float_as_uint(v.z) == POISON) |
                      (__float_as_uint(v.w) == POISON));
}

// src[R][C] -> dst[C][R], 64x64 LDS tiles, grid = (C/64)*(R/64), 256 thr
__global__ void transpose_f32(const float* __restrict__ src, float* __restrict__ dst,
                              int R, int C) {
    __shared__ float tile[64][65];
    const int tcol = threadIdx.x & 63;
    const int trow = threadIdx.x >> 6;
    const int nbx = C >> 6;
    const int bx = blockIdx.x % nbx;
    const int by = blockIdx.x / nbx;
    const int c0 = bx << 6, r0 = by << 6;
    for (int i = trow; i < 64; i += 4)
        tile[i][tcol] = src[(size_t)(r0 + i) * C + c0 + tcol];
    __syncthreads();
    for (int i = trow; i < 64; i += 4)
        dst[(size_t)(c0 + i) * R + r0 + tcol] = tile[tcol][i];
}

#define FMA16(ACC, H)                                   \
    ACC.x = fmaf(w0.x, H.x, ACC.x);                     \
    ACC.y = fmaf(w0.y, H.x, ACC.y);                     \
    ACC.z = fmaf(w0.z, H.x, ACC.z);                     \
    ACC.w = fmaf(w0.w, H.x, ACC.w);                     \
    ACC.x = fmaf(w1.x, H.y, ACC.x);                     \
    ACC.y = fmaf(w1.y, H.y, ACC.y);                     \
    ACC.z = fmaf(w1.z, H.y, ACC.z);                     \
    ACC.w = fmaf(w1.w, H.y, ACC.w);                     \
    ACC.x = fmaf(w2.x, H.z, ACC.x);                     \
    ACC.y = fmaf(w2.y, H.z, ACC.y);                     \
    ACC.z = fmaf(w2.z, H.z, ACC.z);                     \
    ACC.w = fmaf(w2.w, H.z, ACC.w);                     \
    ACC.x = fmaf(w3.x, H.w, ACC.x);                     \
    ACC.y = fmaf(w3.y, H.w, ACC.y);                     \
    ACC.z = fmaf(w3.z, H.w, ACC.z);                     \
    ACC.w = fmaf(w3.w, H.w, ACC.w);

#define RED12(ACC)                                      \
    ACC.x += __shfl_xor(ACC.x, 8);                      \
    ACC.y += __shfl_xor(ACC.y, 8);                      \
    ACC.z += __shfl_xor(ACC.z, 8);                      \
    ACC.w += __shfl_xor(ACC.w, 8);                      \
    ACC.x += __shfl_xor(ACC.x, 16);                     \
    ACC.y += __shfl_xor(ACC.y, 16);                     \
    ACC.z += __shfl_xor(ACC.z, 16);                     \
    ACC.w += __shfl_xor(ACC.w, 16);                     \
    ACC.x += __shfl_xor(ACC.x, 32);                     \
    ACC.y += __shfl_xor(ACC.y, 32);                     \
    ACC.z += __shfl_xor(ACC.z, 32);                     \
    ACC.w += __shfl_xor(ACC.w, 32);

// One phase: consume chain C, issue DMA for chain CN, FMA+reduce+epi.
#define ESN_PHASE(C, XV, DMACOND, DMAT, CN)                                    \
    {                                                                          \
        if (t == 0) {                                                          \
            const float* p = h0 + (size_t)(b0 + 2*(C) + srow) * HDIM           \
                             + krec + sko;                                     \
            *(float4*)(ht##C + hdoff) = *(const float4*)(p);                   \
        } else {                                                               \
            wait_vmem0();                                                      \
            float4 a = *(const float4*)(ht##C + hdoff);                        \
            if (__any((int)chk4(a))) {                                         \
                const float* p = out + ((size_t)(t - 1) * BATCH + b0 + 2*(C)   \
                                 + srow) * HDIM + krec + sko;                  \
                do { sc_load1x4(p, a); } while (__any((int)chk4(a)));          \
                *(float4*)(ht##C + hdoff) = a;                                 \
            }                                                                  \
        }                                                                      \
        if (lane < 32) *(xd##C) = XV;                                          \
        if (DMACOND) {                                                         \
            const float* g = out + ((size_t)(DMAT) * BATCH + b0 + 2*(CN)       \
                             + srow) * HDIM + krec + sko;                      \
            issue_dma16(g, ht##CN + hdoff);                                    \
        }                                                                      \
        if ((t + 1 < T_STEPS) && lane < 32)                                    \
            XV = x[((size_t)(t + 1) * BATCH + b0 + 2*(C) + xr) * IDIM          \
                   + (wave << 4) + xco];                                       \
        float4 acc0 = make_float4(0.f, 0.f, 0.f, 0.f);                         \
        float4 acc1 = make_float4(0.f, 0.f, 0.f, 0.f);                         \
        _Pragma("unroll")                                                      \
        for (int i = 0; i < 4; ++i) {                                          \
            const int ko = ((i << 3) + ksub) << 2;                             \
            const float4 w0 = Wv[i * 4 + 0], w1 = Wv[i * 4 + 1];               \
            const float4 w2 = Wv[i * 4 + 2], w3 = Wv[i * 4 + 3];               \
            float4 h4 = *(const float4*)(hb##C + ko);                          \
            FMA16(acc0, h4)                                                    \
            h4 = *(const float4*)(hb##C + 128 + ko);                           \
            FMA16(acc1, h4)                                                    \
        }                                                                      \
        {                                                                      \
            float2 hx2 = *(const float2*)(xb##C + (ksub << 1));                \
            acc0.x = fmaf(Wv[16].x, hx2.x, acc0.x);                            \
            acc0.y = fmaf(Wv[16].y, hx2.x, acc0.y);                            \
            acc0.z = fmaf(Wv[16].z, hx2.x, acc0.z);                            \
            acc0.w = fmaf(Wv[16].w, hx2.x, acc0.w);                            \
            acc0.x = fmaf(Wv[17].x, hx2.y, acc0.x);                            \
            acc0.y = fmaf(Wv[17].y, hx2.y, acc0.y);                            \
            acc0.z = fmaf(Wv[17].z, hx2.y, acc0.z);                            \
            acc0.w = fmaf(Wv[17].w, hx2.y, acc0.w);                            \
            hx2 = *(const float2*)(xb##C + 16 + (ksub << 1));                  \
            acc1.x = fmaf(Wv[16].x, hx2.x, acc1.x);                            \
            acc1.y = fmaf(Wv[16].y, hx2.x, acc1.y);                            \
            acc1.z = fmaf(Wv[16].z, hx2.x, acc1.z);                            \
            acc1.w = fmaf(Wv[16].w, hx2.x, acc1.w);                            \
            acc1.x = fmaf(Wv[17].x, hx2.y, acc1.x);                            \
            acc1.y = fmaf(Wv[17].y, hx2.y, acc1.y);                            \
            acc1.z = fmaf(Wv[17].z, hx2.y, acc1.z);                            \
            acc1.w = fmaf(Wv[17].w, hx2.y, acc1.w);                            \
        }                                                                      \
        RED12(acc0)                                                            \
        RED12(acc1)                                                            \
        if (ksub == 0) {                                                       \
            red##C[((wave << 3) + jq) * 3 + 0] = acc0;                         \
            red##C[((wave << 3) + jq) * 3 + 1] = acc1;                         \
        }                                                                      \
        __syncthreads();                                                       \
        if (wave < 2 && lane < 8) {                                            \
            float4 s = make_float4(0.f, 0.f, 0.f, 0.f);                        \
            _Pragma("unroll")                                                  \
            for (int w = 0; w < 8; ++w) {                                      \
                float4 r = red##C[((w << 3) + lane) * 3 + wave];               \
                s.x += r.x; s.y += r.y; s.z += r.z; s.w += r.w;                \
            }                                                                  \
            float4 o;                                                          \
            o.x = tanhf(s.x + b4.x);                                           \
            o.y = tanhf(s.y + b4.y);                                           \
            o.z = tanhf(s.z + b4.z);                                           \
            o.w = tanhf(s.w + b4.w);                                           \
            sc_store4_nodrain(out + ((size_t)t * BATCH + b0 + 2*(C) + wave)    \
                              * HDIM + jj, o);                                 \
            if (t == T_STEPS - 1)                                              \
                *(float4*)(hfin + (size_t)(b0 + 2*(C) + wave) * HDIM + jj) = o;\
        }                                                                      \
    }

__global__ __launch_bounds__(512) void esn_persistent(
    const float* __restrict__ x,     // [512][64][128]
    const float* __restrict__ h0,    // [64][1024]
    const float* __restrict__ WT,    // [1152][1024]
    const float* __restrict__ bias,  // [1024]
    float* __restrict__ out,         // [512][64][1024] (pre-poisoned)
    float* __restrict__ hfin)        // [64][1024]
{
    const int tid  = threadIdx.x;
    const int wg   = blockIdx.x;
    const int wave = tid >> 6;                       // 0..7 (k-slice; 0-1 epi row)
    const int lane = tid & 63;
    const int jq   = lane & 7;                       // 4 j each -> 32 j
    const int ksub = lane >> 3;                      // 0..7 k-interleave
    const int jblk = ((wg & 7) << 2) | ((wg >> 3) & 3);  // XCD owns 4 jblks
    const int bgrp = wg >> 5;                            // 0..7
    const int b0   = bgrp << 3;                          // 8 rows: 4 chains x 2
    const int j0   = (jblk << 5) + (jq << 2);
    const int krec = wave << 7;                      // recurrent k base (128/wave)
    const int kx   = HDIM + (wave << 4) + (ksub << 1);  // x-part rows (2 each)

    // chain-private staging (all wave-private within a chain)
    __shared__ float  ht0[8 * 256], ht1[8 * 256], ht2[8 * 256], ht3[8 * 256];
    __shared__ float  hx0[8 * 32],  hx1[8 * 32],  hx2[8 * 32],  hx3[8 * 32];
    __shared__ float4 red0[8 * 8 * 3], red1[8 * 8 * 3];
    __shared__ float4 red2[8 * 8 * 3], red3[8 * 8 * 3];

    // ---- hoist all 18 W float4 loads for ALL 512 steps (72 VGPRs) ----
    float4 Wv[18];
    {
        const float* wp = WT + (size_t)krec * HDIM + j0;
        #pragma unroll
        for (int i = 0; i < 4; ++i) {
            const int kk = ((i << 3) + ksub) << 2;      // 0..124 step 4
            const float* wk = wp + (size_t)kk * HDIM;
            Wv[i * 4 + 0] = *(const float4*)(wk);
            Wv[i * 4 + 1] = *(const float4*)(wk + HDIM);
            Wv[i * 4 + 2] = *(const float4*)(wk + 2 * HDIM);
            Wv[i * 4 + 3] = *(const float4*)(wk + 3 * HDIM);
        }
        const float* wkx = WT + (size_t)kx * HDIM + j0;
        Wv[16] = *(const float4*)(wkx);
        Wv[17] = *(const float4*)(wkx + HDIM);
    }

    // ---- epilogue constants: waves 0-1, lanes 0-7 handle one row/chain ----
    float4 b4 = make_float4(0.f, 0.f, 0.f, 0.f);
    int jj = 0;
    if (lane < 8) {
        jj = (jblk << 5) + (lane << 2);
        b4 = *(const float4*)(bias + jj);
    }

    // ---- staging lane maps (2 rows/chain) ----
    const int srow  = lane >> 5;               // row in chain (0/1)
    const int sko   = (lane & 31) << 2;        // k-offset within slice
    const int hdoff = (wave << 8) + (lane << 2);   // == wave base + lane*16B
    const int xr    = (lane >> 4) & 1;         // x row (lane<32)
    const int xco   = lane & 15;               // x col within 16-slice
    float* xd0 = hx0 + (wave << 5) + (xr << 4) + xco;
    float* xd1 = hx1 + (wave << 5) + (xr << 4) + xco;
    float* xd2 = hx2 + (wave << 5) + (xr << 4) + xco;
    float* xd3 = hx3 + (wave << 5) + (xr << 4) + xco;
    const float* hb0 = ht0 + (wave << 8);
    const float* hb1 = ht1 + (wave << 8);
    const float* hb2 = ht2 + (wave << 8);
    const float* hb3 = ht3 + (wave << 8);
    const float* xb0 = hx0 + (wave << 5);
    const float* xb1 = hx1 + (wave << 5);
    const float* xb2 = hx2 + (wave << 5);
    const float* xb3 = hx3 + (wave << 5);

    // ---- prefetch x slices for t=0 (plain cached loads, lane<32 only) ----
    float xv0 = 0.f, xv1 = 0.f, xv2 = 0.f, xv3 = 0.f;
    if (lane < 32) {
        xv0 = x[(size_t)(b0 + 0 + xr) * IDIM + (wave << 4) + xco];
        xv1 = x[(size_t)(b0 + 2 + xr) * IDIM + (wave << 4) + xco];
        xv2 = x[(size_t)(b0 + 4 + xr) * IDIM + (wave << 4) + xco];
        xv3 = x[(size_t)(b0 + 6 + xr) * IDIM + (wave << 4) + xco];
    }

    for (int t = 0; t < T_STEPS; ++t) {
        ESN_PHASE(0, xv0, (t >= 1), (t - 1), 1)
        ESN_PHASE(1, xv1, (t >= 1), (t - 1), 2)
        ESN_PHASE(2, xv2, (t >= 1), (t - 1), 3)
        ESN_PHASE(3, xv3, (t + 1 < T_STEPS), (t), 0)
    }
}

extern "C" void kernel_launch(void* const* d_in, const int* in_sizes, int n_in,
                              void* d_out, int out_size, void* d_ws, size_t ws_size,
                              hipStream_t stream) {
    const float* x    = (const float*)d_in[0];
    const float* h0   = (const float*)d_in[1];
    const float* w_ih = (const float*)d_in[2];   // [1024][128]
    const float* w_hh = (const float*)d_in[3];   // [1024][1024]
    const float* bias = (const float*)d_in[4];   // [1024]
    float* out = (float*)d_out;

    char* ws = (char*)d_ws;
    float* WT = (float*)ws;                      // [1152][1024] = 4.72 MB

    // poison the polled region: byte 0x7F -> dword 0x7F7F7F7F = 3.4e38,
    // unreachable by tanh. Stream-ordered; re-arms on every replay.
    (void)hipMemsetAsync(out, 0x7F,
                         (size_t)T_STEPS * BATCH * HDIM * sizeof(float), stream);
    transpose_f32<<<256, 256, 0, stream>>>(w_hh, WT, HDIM, HDIM);
    transpose_f32<<<32, 256, 0, stream>>>(w_ih, WT + (size_t)HDIM * HDIM, HDIM, IDIM);
    esn_persistent<<<NWG, 512, 0, stream>>>(x, h0, WT, bias,
                                            out, out + (size_t)T_STEPS * BATCH * HDIM);
}

// Round 20
// 2560.626 us; speedup vs baseline: 1.3013x; 1.3013x over previous
//
#include <hip/hip_runtime.h>
#include <math.h>

// ESN: 512 sequential steps of h = tanh([h | x_t] @ [W_hh|W_ih]^T + b)
// T=512, B=64, I=128, H=1024, K' = 1152.
//
// R24 = R18 (best, 2.55 ms) + s_setprio(1) around the epilogue/publish.
//  * R19-R23 established: publish->observe delta (~2us) is irreducible
//    consumer-side; prefetch attempts (reg-async: unsound; LDS-DMA early:
//    poison retries; LDS-DMA late: flight too short; 4-chain: overhead >
//    savings). R18's 2-chain interleave is the floor-holder.
//  * The one safe lever left: at publish time 7 waves are spamming poll
//    loads; setprio(1) on the epilogue wave starts the delta clock sooner
//    (T5 in its valid regime: waves at different roles).
//
// R18 structure (proven): two independent 4-row chains per WG interleaved
//  {pollA, FMA_A, redA, sync, epiA | pollB, FMA_B, redB, sync, epiB}.
//  A's publish->next-poll gap is filled by B's whole phase and vice versa.
//  * Sentinel sync: out pre-poisoned 0x7F7F7F7F (3.4e38, unreachable by
//    tanh); data IS the flag; consumers retry sc0sc1 loads while any dword
//    is poison; producers fire-and-forget sc0sc1 16B stores (no drain, no
//    flags). Each location written exactly once -> non-poison = final.
//  * Wave-private k-slice staging (no pre-FMA barrier), W (18 float4) +
//    bias VGPR-resident all 512 steps, x prefetch.

#define T_STEPS 512
#define BATCH   64
#define HDIM    1024
#define IDIM    128
#define KDIM    1152
#define NWG     256
#define NB      4
#define POISON  0x7F7F7F7Fu

typedef float f32x4_t __attribute__((ext_vector_type(4)));

// 2 x 16B coherence-point loads from 2 addresses, single drain.
__device__ __forceinline__ void sc_load2x4(const float* p0, const float* p1,
                                           float4& a, float4& b) {
    asm volatile(
        "global_load_dwordx4 %0, %2, off sc0 sc1\n\t"
        "global_load_dwordx4 %1, %3, off sc0 sc1\n\t"
        "s_waitcnt vmcnt(0)"
        : "=&v"(a), "=&v"(b)
        : "v"(p0), "v"(p1)
        : "memory");
}

// 16B write-through store (no drain: visibility rides the write; consumers
// poll the data itself)
__device__ __forceinline__ void sc_store4_nodrain(float* p, float4 v) {
    f32x4_t t;
    t.x = v.x; t.y = v.y; t.z = v.z; t.w = v.w;
    asm volatile("global_store_dwordx4 %0, %1, off sc0 sc1"
                 :: "v"(p), "v"(t) : "memory");
}

__device__ __forceinline__ unsigned chk4(float4 v) {
    return (unsigned)((__float_as_uint(v.x) == POISON) |
                      (__float_as_uint(v.y) == POISON) |
                      (__float_as_uint(v.z) == POISON) |
                      (__float_as_uint(v.w) == POISON));
}

// src[R][C] -> dst[C][R], 64x64 LDS tiles, grid = (C/64)*(R/64), 256 thr
__global__ void transpose_f32(const float* __restrict__ src, float* __restrict__ dst,
                              int R, int C) {
    __shared__ float tile[64][65];
    const int tcol = threadIdx.x & 63;
    const int trow = threadIdx.x >> 6;
    const int nbx = C >> 6;
    const int bx = blockIdx.x % nbx;
    const int by = blockIdx.x / nbx;
    const int c0 = bx << 6, r0 = by << 6;
    for (int i = trow; i < 64; i += 4)
        tile[i][tcol] = src[(size_t)(r0 + i) * C + c0 + tcol];
    __syncthreads();
    for (int i = trow; i < 64; i += 4)
        dst[(size_t)(c0 + i) * R + r0 + tcol] = tile[tcol][i];
}

__global__ __launch_bounds__(512) void esn_persistent(
    const float* __restrict__ x,     // [512][64][128]
    const float* __restrict__ h0,    // [64][1024]
    const float* __restrict__ WT,    // [1152][1024]
    const float* __restrict__ bias,  // [1024]
    float* __restrict__ out,         // [512][64][1024] (pre-poisoned)
    float* __restrict__ hfin)        // [64][1024]
{
    const int tid  = threadIdx.x;
    const int wg   = blockIdx.x;
    const int wave = tid >> 6;                       // 0..7 (k-slice; 0-3 epi row)
    const int lane = tid & 63;
    const int jq   = lane & 7;                       // 4 j each -> 32 j
    const int ksub = lane >> 3;                      // 0..7 k-interleave
    const int jblk = ((wg & 7) << 2) | ((wg >> 3) & 3);  // XCD owns 4 jblks
    const int bgrp = wg >> 5;                            // 0..7
    const int b0   = bgrp << 3;                          // 8 rows: A=0..3, B=4..7
    const int j0   = (jblk << 5) + (jq << 2);
    const int krec = wave << 7;                      // recurrent k base (128/wave)
    const int kx   = HDIM + (wave << 4) + (ksub << 1);  // x-part rows (2 each)

    // chain-private staging blocks
    __shared__ float  htA[8 * 512];                  // [wave][4 rows][128 k] 16KB
    __shared__ float  htB[8 * 512];                  // 16KB
    __shared__ float  hxA[8 * 64];                   // [wave][4 rows][16 xk]  2KB
    __shared__ float  hxB[8 * 64];                   //  2KB
    __shared__ float4 redA[8 * 8 * 5];               // [w][jq] stride 5       5KB
    __shared__ float4 redB[8 * 8 * 5];               //  5KB

    // ---- hoist all 18 W float4 loads for ALL 512 steps (72 VGPRs) ----
    float4 Wv[18];
    {
        const float* wp = WT + (size_t)krec * HDIM + j0;
        #pragma unroll
        for (int i = 0; i < 4; ++i) {
            const int kk = ((i << 3) + ksub) << 2;      // 0..124 step 4
            const float* wk = wp + (size_t)kk * HDIM;
            Wv[i * 4 + 0] = *(const float4*)(wk);
            Wv[i * 4 + 1] = *(const float4*)(wk + HDIM);
            Wv[i * 4 + 2] = *(const float4*)(wk + 2 * HDIM);
            Wv[i * 4 + 3] = *(const float4*)(wk + 3 * HDIM);
        }
        const float* wkx = WT + (size_t)kx * HDIM + j0;
        Wv[16] = *(const float4*)(wkx);
        Wv[17] = *(const float4*)(wkx + HDIM);
    }

    // ---- epilogue constants: waves 0-3 lanes 0-7 handle one row/chain ----
    float4 b4 = make_float4(0.f, 0.f, 0.f, 0.f);
    int jj = 0;
    if (lane < 8) {
        jj = (jblk << 5) + (lane << 2);
        b4 = *(const float4*)(bias + jj);
    }

    // ---- staging lane maps (4 rows/chain: lane covers rows sbb, sbb+2) ----
    const int sbb = lane >> 5;                 // row parity (0/1)
    const int sko = (lane & 31) << 2;          // k-offset within slice
    float* hdA = htA + (wave << 9) + (sbb << 7) + sko;
    float* hdB = htB + (wave << 9) + (sbb << 7) + sko;
    const int xr = lane >> 4;                  // x row 0..3
    const int xco = lane & 15;                 // x col within 16-slice
    float* xdA = hxA + (wave << 6) + (xr << 4) + xco;
    float* xdB = hxB + (wave << 6) + (xr << 4) + xco;
    const float* hbA = htA + (wave << 9);
    const float* hbB = htB + (wave << 9);
    const float* xbA = hxA + (wave << 6);
    const float* xbB = hxB + (wave << 6);

    // ---- prefetch x slices for t=0 (plain cached loads, x read-only) ----
    float xvA = x[(size_t)(b0 + xr) * IDIM + (wave << 4) + xco];
    float xvB = x[(size_t)(b0 + 4 + xr) * IDIM + (wave << 4) + xco];

    for (int t = 0; t < T_STEPS; ++t) {
        // ================= chain A (rows b0..b0+3) =================
        *xdA = xvA;
        if (t == 0) {
            const float* p = h0 + (size_t)(b0 + sbb) * HDIM + krec + sko;
            *(float4*)(hdA)       = *(const float4*)(p);
            *(float4*)(hdA + 256) = *(const float4*)(p + 2 * HDIM);
        } else {
            const float* p = out + ((size_t)(t - 1) * BATCH + b0 + sbb) * HDIM
                             + krec + sko;
            float4 a, b;
            do { sc_load2x4(p, p + 2 * HDIM, a, b); }
            while (__any((int)(chk4(a) | chk4(b))));
            *(float4*)(hdA)       = a;
            *(float4*)(hdA + 256) = b;
        }
        if (t + 1 < T_STEPS)
            xvA = x[((size_t)(t + 1) * BATCH + b0 + xr) * IDIM + (wave << 4) + xco];

        {
            float4 acc[NB];
            #pragma unroll
            for (int bb = 0; bb < NB; ++bb) acc[bb] = make_float4(0.f, 0.f, 0.f, 0.f);
            #pragma unroll
            for (int i = 0; i < 4; ++i) {
                const int ko = ((i << 3) + ksub) << 2;
                const float4 w0 = Wv[i * 4 + 0], w1 = Wv[i * 4 + 1];
                const float4 w2 = Wv[i * 4 + 2], w3 = Wv[i * 4 + 3];
                #pragma unroll
                for (int bb = 0; bb < NB; ++bb) {
                    float4 h4 = *(const float4*)(hbA + (bb << 7) + ko);
                    acc[bb].x = fmaf(w0.x, h4.x, acc[bb].x);
                    acc[bb].y = fmaf(w0.y, h4.x, acc[bb].y);
                    acc[bb].z = fmaf(w0.z, h4.x, acc[bb].z);
                    acc[bb].w = fmaf(w0.w, h4.x, acc[bb].w);
                    acc[bb].x = fmaf(w1.x, h4.y, acc[bb].x);
                    acc[bb].y = fmaf(w1.y, h4.y, acc[bb].y);
                    acc[bb].z = fmaf(w1.z, h4.y, acc[bb].z);
                    acc[bb].w = fmaf(w1.w, h4.y, acc[bb].w);
                    acc[bb].x = fmaf(w2.x, h4.z, acc[bb].x);
                    acc[bb].y = fmaf(w2.y, h4.z, acc[bb].y);
                    acc[bb].z = fmaf(w2.z, h4.z, acc[bb].z);
                    acc[bb].w = fmaf(w2.w, h4.z, acc[bb].w);
                    acc[bb].x = fmaf(w3.x, h4.w, acc[bb].x);
                    acc[bb].y = fmaf(w3.y, h4.w, acc[bb].y);
                    acc[bb].z = fmaf(w3.z, h4.w, acc[bb].z);
                    acc[bb].w = fmaf(w3.w, h4.w, acc[bb].w);
                }
            }
            #pragma unroll
            for (int bb = 0; bb < NB; ++bb) {
                float2 hx = *(const float2*)(xbA + (bb << 4) + (ksub << 1));
                acc[bb].x = fmaf(Wv[16].x, hx.x, acc[bb].x);
                acc[bb].y = fmaf(Wv[16].y, hx.x, acc[bb].y);
                acc[bb].z = fmaf(Wv[16].z, hx.x, acc[bb].z);
                acc[bb].w = fmaf(Wv[16].w, hx.x, acc[bb].w);
                acc[bb].x = fmaf(Wv[17].x, hx.y, acc[bb].x);
                acc[bb].y = fmaf(Wv[17].y, hx.y, acc[bb].y);
                acc[bb].z = fmaf(Wv[17].z, hx.y, acc[bb].z);
                acc[bb].w = fmaf(Wv[17].w, hx.y, acc[bb].w);
            }
            #pragma unroll
            for (int bb = 0; bb < NB; ++bb) {
                acc[bb].x += __shfl_xor(acc[bb].x, 8);
                acc[bb].y += __shfl_xor(acc[bb].y, 8);
                acc[bb].z += __shfl_xor(acc[bb].z, 8);
                acc[bb].w += __shfl_xor(acc[bb].w, 8);
                acc[bb].x += __shfl_xor(acc[bb].x, 16);
                acc[bb].y += __shfl_xor(acc[bb].y, 16);
                acc[bb].z += __shfl_xor(acc[bb].z, 16);
                acc[bb].w += __shfl_xor(acc[bb].w, 16);
                acc[bb].x += __shfl_xor(acc[bb].x, 32);
                acc[bb].y += __shfl_xor(acc[bb].y, 32);
                acc[bb].z += __shfl_xor(acc[bb].z, 32);
                acc[bb].w += __shfl_xor(acc[bb].w, 32);
            }
            if (ksub == 0) {
                #pragma unroll
                for (int bb = 0; bb < NB; ++bb)
                    redA[((wave << 3) + jq) * 5 + bb] = acc[bb];
            }
        }
        __syncthreads();                               // redA(t) complete
        if (wave < 4 && lane < 8) {
            __builtin_amdgcn_s_setprio(1);             // publish ASAP (T5)
            float4 s = make_float4(0.f, 0.f, 0.f, 0.f);
            #pragma unroll
            for (int w = 0; w < 8; ++w) {
                float4 r = redA[((w << 3) + lane) * 5 + wave];
                s.x += r.x; s.y += r.y; s.z += r.z; s.w += r.w;
            }
            float4 o;
            o.x = tanhf(s.x + b4.x);
            o.y = tanhf(s.y + b4.y);
            o.z = tanhf(s.z + b4.z);
            o.w = tanhf(s.w + b4.w);
            sc_store4_nodrain(out + ((size_t)t * BATCH + b0 + wave) * HDIM + jj, o);
            __builtin_amdgcn_s_setprio(0);
            if (t == T_STEPS - 1)
                *(float4*)(hfin + (size_t)(b0 + wave) * HDIM + jj) = o;
        }

        // ================= chain B (rows b0+4..b0+7) =================
        *xdB = xvB;
        if (t == 0) {
            const float* p = h0 + (size_t)(b0 + 4 + sbb) * HDIM + krec + sko;
            *(float4*)(hdB)       = *(const float4*)(p);
            *(float4*)(hdB + 256) = *(const float4*)(p + 2 * HDIM);
        } else {
            const float* p = out + ((size_t)(t - 1) * BATCH + b0 + 4 + sbb) * HDIM
                             + krec + sko;
            float4 a, b;
            do { sc_load2x4(p, p + 2 * HDIM, a, b); }
            while (__any((int)(chk4(a) | chk4(b))));
            *(float4*)(hdB)       = a;
            *(float4*)(hdB + 256) = b;
        }
        if (t + 1 < T_STEPS)
            xvB = x[((size_t)(t + 1) * BATCH + b0 + 4 + xr) * IDIM
                    + (wave << 4) + xco];

        {
            float4 acc[NB];
            #pragma unroll
            for (int bb = 0; bb < NB; ++bb) acc[bb] = make_float4(0.f, 0.f, 0.f, 0.f);
            #pragma unroll
            for (int i = 0; i < 4; ++i) {
                const int ko = ((i << 3) + ksub) << 2;
                const float4 w0 = Wv[i * 4 + 0], w1 = Wv[i * 4 + 1];
                const float4 w2 = Wv[i * 4 + 2], w3 = Wv[i * 4 + 3];
                #pragma unroll
                for (int bb = 0; bb < NB; ++bb) {
                    float4 h4 = *(const float4*)(hbB + (bb << 7) + ko);
                    acc[bb].x = fmaf(w0.x, h4.x, acc[bb].x);
                    acc[bb].y = fmaf(w0.y, h4.x, acc[bb].y);
                    acc[bb].z = fmaf(w0.z, h4.x, acc[bb].z);
                    acc[bb].w = fmaf(w0.w, h4.x, acc[bb].w);
                    acc[bb].x = fmaf(w1.x, h4.y, acc[bb].x);
                    acc[bb].y = fmaf(w1.y, h4.y, acc[bb].y);
                    acc[bb].z = fmaf(w1.z, h4.y, acc[bb].z);
                    acc[bb].w = fmaf(w1.w, h4.y, acc[bb].w);
                    acc[bb].x = fmaf(w2.x, h4.z, acc[bb].x);
                    acc[bb].y = fmaf(w2.y, h4.z, acc[bb].y);
                    acc[bb].z = fmaf(w2.z, h4.z, acc[bb].z);
                    acc[bb].w = fmaf(w2.w, h4.z, acc[bb].w);
                    acc[bb].x = fmaf(w3.x, h4.w, acc[bb].x);
                    acc[bb].y = fmaf(w3.y, h4.w, acc[bb].y);
                    acc[bb].z = fmaf(w3.z, h4.w, acc[bb].z);
                    acc[bb].w = fmaf(w3.w, h4.w, acc[bb].w);
                }
            }
            #pragma unroll
            for (int bb = 0; bb < NB; ++bb) {
                float2 hx = *(const float2*)(xbB + (bb << 4) + (ksub << 1));
                acc[bb].x = fmaf(Wv[16].x, hx.x, acc[bb].x);
                acc[bb].y = fmaf(Wv[16].y, hx.x, acc[bb].y);
                acc[bb].z = fmaf(Wv[16].z, hx.x, acc[bb].z);
                acc[bb].w = fmaf(Wv[16].w, hx.x, acc[bb].w);
                acc[bb].x = fmaf(Wv[17].x, hx.y, acc[bb].x);
                acc[bb].y = fmaf(Wv[17].y, hx.y, acc[bb].y);
                acc[bb].z = fmaf(Wv[17].z, hx.y, acc[bb].z);
                acc[bb].w = fmaf(Wv[17].w, hx.y, acc[bb].w);
            }
            #pragma unroll
            for (int bb = 0; bb < NB; ++bb) {
                acc[bb].x += __shfl_xor(acc[bb].x, 8);
                acc[bb].y += __shfl_xor(acc[bb].y, 8);
                acc[bb].z += __shfl_xor(acc[bb].z, 8);
                acc[bb].w += __shfl_xor(acc[bb].w, 8);
                acc[bb].x += __shfl_xor(acc[bb].x, 16);
                acc[bb].y += __shfl_xor(acc[bb].y, 16);
                acc[bb].z += __shfl_xor(acc[bb].z, 16);
                acc[bb].w += __shfl_xor(acc[bb].w, 16);
                acc[bb].x += __shfl_xor(acc[bb].x, 32);
                acc[bb].y += __shfl_xor(acc[bb].y, 32);
                acc[bb].z += __shfl_xor(acc[bb].z, 32);
                acc[bb].w += __shfl_xor(acc[bb].w, 32);
            }
            if (ksub == 0) {
                #pragma unroll
                for (int bb = 0; bb < NB; ++bb)
                    redB[((wave << 3) + jq) * 5 + bb] = acc[bb];
            }
        }
        __syncthreads();                               // redB(t) complete
        if (wave < 4 && lane < 8) {
            __builtin_amdgcn_s_setprio(1);             // publish ASAP (T5)
            float4 s = make_float4(0.f, 0.f, 0.f, 0.f);
            #pragma unroll
            for (int w = 0; w < 8; ++w) {
                float4 r = redB[((w << 3) + lane) * 5 + wave];
                s.x += r.x; s.y += r.y; s.z += r.z; s.w += r.w;
            }
            float4 o;
            o.x = tanhf(s.x + b4.x);
            o.y = tanhf(s.y + b4.y);
            o.z = tanhf(s.z + b4.z);
            o.w = tanhf(s.w + b4.w);
            sc_store4_nodrain(out + ((size_t)t * BATCH + b0 + 4 + wave) * HDIM + jj, o);
            __builtin_amdgcn_s_setprio(0);
            if (t == T_STEPS - 1)
                *(float4*)(hfin + (size_t)(b0 + 4 + wave) * HDIM + jj) = o;
        }
    }
}

extern "C" void kernel_launch(void* const* d_in, const int* in_sizes, int n_in,
                              void* d_out, int out_size, void* d_ws, size_t ws_size,
                              hipStream_t stream) {
    const float* x    = (const float*)d_in[0];
    const float* h0   = (const float*)d_in[1];
    const float* w_ih = (const float*)d_in[2];   // [1024][128]
    const float* w_hh = (const float*)d_in[3];   // [1024][1024]
    const float* bias = (const float*)d_in[4];   // [1024]
    float* out = (float*)d_out;

    char* ws = (char*)d_ws;
    float* WT = (float*)ws;                      // [1152][1024] = 4.72 MB

    // poison the polled region: byte 0x7F -> dword 0x7F7F7F7F = 3.4e38,
    // unreachable by tanh. Stream-ordered; re-arms on every replay.
    (void)hipMemsetAsync(out, 0x7F,
                         (size_t)T_STEPS * BATCH * HDIM * sizeof(float), stream);
    transpose_f32<<<256, 256, 0, stream>>>(w_hh, WT, HDIM, HDIM);
    transpose_f32<<<32, 256, 0, stream>>>(w_ih, WT + (size_t)HDIM * HDIM, HDIM, IDIM);
    esn_persistent<<<NWG, 512, 0, stream>>>(x, h0, WT, bias,
                                            out, out + (size_t)T_STEPS * BATCH * HDIM);
}